// Round 9
// baseline (62.047 us; speedup 1.0000x reference)
//
#include <hip/hip_runtime.h>
#include <hip/hip_bf16.h>

// CrossAttenFusion: q=x@Wq*scale, k=ctx@Wk, v=ctx@Wv (bf16 MFMA proj) -> bf16 ws
// (K tiled + XOR-swizzled; V tiled + sigma-permuted key order + XOR-swizzled);
// flash attention with 32x32x16 MFMAs, split P-way over keys (additive partial
// softmax: scores bounded, no max tracking), 2-buffer LDS pipeline with counted
// vmcnt; combine kernel normalizes and applies Wo+bo via MFMA.
// B=8, N=Nc=3136, C=inner=64, H=2, D=32.

constexpr int Bc = 8;
constexpr int Nq = 3136;
constexpr int NT = 49;                           // 64-key tiles per batch
constexpr size_t SEG   = (size_t)Bc * Nq * 64;   // shorts per ws segment
constexpr size_t OPOFF = 3 * SEG;                // O-parts (_Float16), <=1176*4096
constexpr size_t LPOFF = OPOFF + (size_t)1176 * 4096;  // l-parts (f32), <=1176*128
constexpr size_t WS_NEED3 = (LPOFF + (size_t)1176 * 256) * 2;  // bytes if P=3

typedef short bf16x8 __attribute__((ext_vector_type(8)));
typedef float f32x4  __attribute__((ext_vector_type(4)));
typedef float f32x16 __attribute__((ext_vector_type(16)));
typedef float f32x2  __attribute__((ext_vector_type(2)));

// scale * log2(e): softmax_e(s*scale) == softmax_2(s*scale*log2e)
#define QSCALE (0.17677669529663687f * 1.4426950408889634f)

__device__ inline unsigned int f2bf(float f) {
    __hip_bfloat16 h = __float2bfloat16(f);
    unsigned short u;
    __builtin_memcpy(&u, &h, 2);
    return (unsigned int)u;
}

// packed f32x2 -> bf16x2 (one VALU op)
__device__ inline unsigned int cvtpk(float lo, float hi) {
    unsigned int r;
    asm("v_cvt_pk_bf16_f32 %0, %1, %2" : "=v"(r) : "v"(lo), "v"(hi));
    return r;
}

__device__ inline float exp2_hw(float x) { return __builtin_amdgcn_exp2f(x); }

#define GLOAD16(gp, lp)                                                        \
    __builtin_amdgcn_global_load_lds(                                          \
        (const __attribute__((address_space(1))) unsigned int*)(gp),           \
        (__attribute__((address_space(3))) unsigned int*)(lp), 16, 0, 0)

// ---------------------------------------------------------------------------
// Kernel 1: projections via MFMA.  Block = 128 rows x 64 cols, 4 waves.
//   m=0: Qs[row][64] = bf16(x@Wq * QSCALE)                       (row-major)
//   m=1: Kt tile: bytes o = (key*128 + d*2) ^ ((key&7)<<4)
//   m=2: Vt tile: bytes o = (d*128 + g16*32 + pos*2) ^ ((d&7)<<4)
//        where g16 = key>>4, pos = (key&3) + 4*sigma_b((key>>2)&3),
//        sigma_b = {0,2,1,3} (bit-swap) -- matches 32x32 PV A-fragment k-order.
// ---------------------------------------------------------------------------
__global__ __launch_bounds__(256)
void proj_kernel(const float* __restrict__ x, const float* __restrict__ ctx,
                 const float* __restrict__ Wq, const float* __restrict__ Wk,
                 const float* __restrict__ Wv, unsigned short* __restrict__ ws) {
    __shared__ short Xls[128 * 72];   // rows padded to 72 shorts (144 B)
    __shared__ short Wtl[64 * 72];    // W^T: [col][k]

    const int m = blockIdx.y;
    const float* in = (m == 0) ? x : ctx;
    const float* W  = (m == 0) ? Wq : (m == 1 ? Wk : Wv);
    const size_t row0 = (size_t)blockIdx.x * 128;
    const int tid = threadIdx.x;

    {
        const int k  = tid & 63;
        const int cb = tid >> 6;
        const float* wr = W + k * 64 + cb * 16;
        float4 w0 = *(const float4*)(wr + 0);
        float4 w1 = *(const float4*)(wr + 4);
        float4 w2 = *(const float4*)(wr + 8);
        float4 w3 = *(const float4*)(wr + 12);
        float wv[16] = {w0.x,w0.y,w0.z,w0.w, w1.x,w1.y,w1.z,w1.w,
                        w2.x,w2.y,w2.z,w2.w, w3.x,w3.y,w3.z,w3.w};
#pragma unroll
        for (int j = 0; j < 16; ++j)
            Wtl[(cb * 16 + j) * 72 + k] = (short)f2bf(wv[j]);
    }
    {
        const int r    = tid >> 1;
        const int half = tid & 1;
        const float* xr = in + (row0 + r) * 64 + half * 32;
        unsigned int u[16];
#pragma unroll
        for (int i = 0; i < 8; ++i) {
            float4 v = *(const float4*)(xr + 4 * i);
            u[2*i]   = f2bf(v.x) | (f2bf(v.y) << 16);
            u[2*i+1] = f2bf(v.z) | (f2bf(v.w) << 16);
        }
        char* dst = (char*)Xls + r * 144 + half * 64;
#pragma unroll
        for (int c = 0; c < 4; ++c)
            *(uint4*)(dst + 16 * c) = make_uint4(u[4*c], u[4*c+1], u[4*c+2], u[4*c+3]);
    }
    __syncthreads();

    const int lane = tid & 63;
    const int w    = tid >> 6;
    const int l15  = lane & 15;
    const int g    = lane >> 4;

    f32x4 acc[2][4];
#pragma unroll
    for (int ti = 0; ti < 2; ++ti)
#pragma unroll
        for (int tc = 0; tc < 4; ++tc) acc[ti][tc] = (f32x4){0.f,0.f,0.f,0.f};

#pragma unroll
    for (int kk = 0; kk < 2; ++kk) {
#pragma unroll
        for (int ti = 0; ti < 2; ++ti) {
            const int T = 2 * w + ti;
            bf16x8 a = *(const bf16x8*)((char*)Xls + (16 * T + l15) * 144 + kk * 64 + 16 * g);
#pragma unroll
            for (int tc = 0; tc < 4; ++tc) {
                bf16x8 bfr = *(const bf16x8*)((char*)Wtl + (16 * tc + l15) * 144 + kk * 64 + 16 * g);
                acc[ti][tc] = __builtin_amdgcn_mfma_f32_16x16x32_bf16(a, bfr, acc[ti][tc], 0, 0, 0);
            }
        }
    }

    unsigned short* Qs = ws;
    char* Ktc = (char*)(ws + SEG);
    char* Vtc = (char*)(ws + 2 * SEG);

#pragma unroll
    for (int ti = 0; ti < 2; ++ti) {
#pragma unroll
        for (int tc = 0; tc < 4; ++tc) {
            const int col = 16 * tc + l15;
            if (m == 0) {
#pragma unroll
                for (int r = 0; r < 4; ++r) {
                    const size_t grow = row0 + 32 * w + 16 * ti + 4 * g + r;
                    Qs[grow * 64 + col] = (unsigned short)f2bf(acc[ti][tc][r] * QSCALE);
                }
            } else if (m == 1) {
#pragma unroll
                for (int r = 0; r < 4; ++r) {
                    const size_t grow = row0 + 32 * w + 16 * ti + 4 * g + r;
                    const size_t tile = grow >> 6;
                    const int key = (int)(grow & 63);
                    const int off = (key * 128 + col * 2) ^ ((key & 7) << 4);
                    *(unsigned short*)(Ktc + tile * 8192 + off) =
                        (unsigned short)f2bf(acc[ti][tc][r]);
                }
            } else {
                // 4 consecutive keys -> one 8B store at sigma-permuted position
                const size_t grow0 = row0 + 32 * w + 16 * ti + 4 * g;
                const size_t tile = grow0 >> 6;
                const int key0 = (int)(grow0 & 63);
                const int kb = (key0 >> 2) & 3;
                const int sb = ((kb & 1) << 1) | (kb >> 1);   // sigma_b bit swap
                const int off = (col * 128 + (key0 >> 4) * 32 + sb * 8)
                                ^ ((col & 7) << 4);
                uint2 pv;
                pv.x = f2bf(acc[ti][tc][0]) | (f2bf(acc[ti][tc][1]) << 16);
                pv.y = f2bf(acc[ti][tc][2]) | (f2bf(acc[ti][tc][3]) << 16);
                *(uint2*)(Vtc + tile * 8192 + off) = pv;
            }
        }
    }
}

// ---------------------------------------------------------------------------
// Kernel 2: flash attention partials (32x32x16 MFMA, 2-buffer LDS, counted
// vmcnt).  Grid 392*P: b=bid&7 (XCD-pinned), idx=bid>>3: qt=idx/P, part=idx%P.
// Wave w: head h=w&1, q-half=w>>1; wave owns 32 q rows (l31) x 32 d (head).
// Per 64-key tile: 4 K b128 + 4 V b128 reads, 4 QK + 4 PV MFMAs, 32 exp2,
// 16 cvtpk; l[q] is lane-local (32x32 S^T col = q) -> float2 adds + one shfl.
// ---------------------------------------------------------------------------
__global__ __launch_bounds__(256)
void flash_kernel(unsigned short* __restrict__ ws, int P) {
    __shared__ __align__(16) char pool[32768];   // K[2][8192] | V[2][8192]
    char* Kpool = pool;
    char* Vpool = pool + 16384;

    const int tid  = threadIdx.x;
    const int lane = tid & 63;
    const int w    = tid >> 6;
    const int h    = w & 1;
    const int half = w >> 1;
    const int l31  = lane & 31;
    const int hi   = lane >> 5;
    const int bid  = blockIdx.x;
    const int b    = bid & 7;
    const int idx  = bid >> 3;
    const int qt   = idx / P;
    const int part = idx - qt * P;
    const int q0   = qt * 64;
    const int base = NT / P, rem = NT - base * P;
    const int t0   = part * base + (part < rem ? part : rem);
    const int tend = t0 + base + (part < rem ? 1 : 0);

    const char* Ktb = (const char*)(ws + SEG)     + (size_t)b * NT * 8192;
    const char* Vtb = (const char*)(ws + 2 * SEG) + (size_t)b * NT * 8192;

    // Q B-frags: lane (col=q=l31, hi) k-slot j -> d = h*32 + dd*16 + 8hi + j
    const unsigned short* qrow =
        ws + ((size_t)(b * Nq + q0 + half * 32 + l31)) * 64 + h * 32 + hi * 8;
    const bf16x8 qf0 = *(const bf16x8*)qrow;          // dd=0
    const bf16x8 qf1 = *(const bf16x8*)(qrow + 16);   // dd=1

    // swizzled LDS offsets (XOR folds into sub-row bits only)
    const int sw    = (l31 & 7) << 4;
    const int koff0 = l31 * 128 + ((h * 64 +      hi * 16) ^ sw);
    const int koff1 = l31 * 128 + ((h * 64 + 32 + hi * 16) ^ sw);
    const int vrow  = (h * 32 + l31) * 128;
    int vg[4];
#pragma unroll
    for (int m2 = 0; m2 < 4; ++m2) vg[m2] = (m2 * 32 + hi * 16) ^ sw;
    const int stoff = tid * 16;

    union VF { bf16x8 v; unsigned int u[4]; };

    f32x16 oacc = {0.f,0.f,0.f,0.f,0.f,0.f,0.f,0.f,
                   0.f,0.f,0.f,0.f,0.f,0.f,0.f,0.f};
    f32x2 lacc = {0.f, 0.f};
    const f32x16 Z16 = {0.f,0.f,0.f,0.f,0.f,0.f,0.f,0.f,
                        0.f,0.f,0.f,0.f,0.f,0.f,0.f,0.f};

    // prologue: issue tiles t0, t0+1 (8 loads); wait t0; barrier
#pragma unroll
    for (int i = 0; i < 2; ++i) {
        const char* ks = Ktb + (size_t)(t0 + i) * 8192;
        const char* vs = Vtb + (size_t)(t0 + i) * 8192;
        GLOAD16(ks + stoff,        Kpool + i * 8192 + stoff);
        GLOAD16(ks + stoff + 4096, Kpool + i * 8192 + stoff + 4096);
        GLOAD16(vs + stoff,        Vpool + i * 8192 + stoff);
        GLOAD16(vs + stoff + 4096, Vpool + i * 8192 + stoff + 4096);
    }
    asm volatile("s_waitcnt vmcnt(4)" ::: "memory");
    __builtin_amdgcn_s_barrier();
    __builtin_amdgcn_sched_barrier(0);

#pragma unroll 1
    for (int t = t0; t < tend; ++t) {
        const int cb = (t - t0) & 1;
        const char* Kb = Kpool + cb * 8192;
        const char* Vb = Vpool + cb * 8192;

        __builtin_amdgcn_s_setprio(1);
#pragma unroll
        for (int c2 = 0; c2 < 2; ++c2) {
            bf16x8 k0 = *(const bf16x8*)(Kb + c2 * 4096 + koff0);
            bf16x8 k1 = *(const bf16x8*)(Kb + c2 * 4096 + koff1);

            // S^T[key][q=l31]: accumulate D=32 over two dd frags
            f32x16 s = __builtin_amdgcn_mfma_f32_32x32x16_bf16(k0, qf0, Z16, 0, 0, 0);
            s = __builtin_amdgcn_mfma_f32_32x32x16_bf16(k1, qf1, s, 0, 0, 0);

            float p[16];
#pragma unroll
            for (int i = 0; i < 16; ++i) p[i] = exp2_hw(s[i]);

            lacc += (f32x2){p[0], p[1]};   lacc += (f32x2){p[2], p[3]};
            lacc += (f32x2){p[4], p[5]};   lacc += (f32x2){p[6], p[7]};
            lacc += (f32x2){p[8], p[9]};   lacc += (f32x2){p[10], p[11]};
            lacc += (f32x2){p[12], p[13]}; lacc += (f32x2){p[14], p[15]};

            VF a0, a1;
            a0.u[0] = cvtpk(p[0], p[1]);   a0.u[1] = cvtpk(p[2], p[3]);
            a0.u[2] = cvtpk(p[4], p[5]);   a0.u[3] = cvtpk(p[6], p[7]);
            a1.u[0] = cvtpk(p[8], p[9]);   a1.u[1] = cvtpk(p[10], p[11]);
            a1.u[2] = cvtpk(p[12], p[13]); a1.u[3] = cvtpk(p[14], p[15]);

            bf16x8 v0 = *(const bf16x8*)(Vb + vrow + vg[2 * c2]);
            bf16x8 v1 = *(const bf16x8*)(Vb + vrow + vg[2 * c2 + 1]);

            oacc = __builtin_amdgcn_mfma_f32_32x32x16_bf16(a0.v, v0, oacc, 0, 0, 0);
            oacc = __builtin_amdgcn_mfma_f32_32x32x16_bf16(a1.v, v1, oacc, 0, 0, 0);
        }
        __builtin_amdgcn_s_setprio(0);

        if (t + 1 < tend) {
            __builtin_amdgcn_s_barrier();        // all readers done with buf cb
            __builtin_amdgcn_sched_barrier(0);
            if (t + 2 < tend) {                  // refill buf cb with tile t+2
                const char* ks = Ktb + (size_t)(t + 2) * 8192;
                const char* vs = Vtb + (size_t)(t + 2) * 8192;
                GLOAD16(ks + stoff,        Kb + stoff);
                GLOAD16(ks + stoff + 4096, Kb + stoff + 4096);
                GLOAD16(vs + stoff,        Vb + stoff);
                GLOAD16(vs + stoff + 4096, Vb + stoff + 4096);
                asm volatile("s_waitcnt vmcnt(4)" ::: "memory");
            } else {
                asm volatile("s_waitcnt vmcnt(0)" ::: "memory");
            }
            __builtin_amdgcn_s_barrier();        // tile t+1 fully landed
            __builtin_amdgcn_sched_barrier(0);
        }
    }

    // ---- epilogue: store partial l and partial O ----
    float lsum = lacc[0] + lacc[1];
    lsum += __shfl_xor(lsum, 32);                // combine the two hi halves
    float* lp = (float*)(ws + LPOFF) + (size_t)bid * 128;
    if (hi == 0) lp[h * 64 + half * 32 + l31] = lsum;

    _Float16* Op = (_Float16*)(ws + OPOFF) + (size_t)bid * 4096;
#pragma unroll
    for (int r = 0; r < 16; ++r) {
        const int q = half * 32 + (r & 3) + 8 * (r >> 2) + 4 * hi;
        Op[q * 64 + h * 32 + l31] = (_Float16)oacc[r];
    }
}

// ---------------------------------------------------------------------------
// Kernel 3: combine P partials + output projection.
// Grid 392: b = cid&7 (same XCD as producers), qt = cid>>3.
// attn = (sum_p O_p) / (sum_p l_p) -> bf16 As -> MFMA @Wo + bo -> out.
// ---------------------------------------------------------------------------
__global__ __launch_bounds__(256)
void combine_kernel(const unsigned short* __restrict__ ws, const float* __restrict__ Wo,
                    const float* __restrict__ bo, float* __restrict__ out, int P) {
    __shared__ short As[64 * 72];
    __shared__ short Wtl[64 * 72];

    const int tid = threadIdx.x;
    const int cid = blockIdx.x;
    const int b   = cid & 7;
    const int qt  = cid >> 3;
    const int q0  = qt * 64;

    const int bid0 = ((qt * P) << 3) | b;        // part p -> bid0 + 8p

    {
        const int k  = tid & 63;
        const int cb = tid >> 6;
        const float* wr = Wo + k * 64 + cb * 16;
        float4 w0 = *(const float4*)(wr + 0);
        float4 w1 = *(const float4*)(wr + 4);
        float4 w2 = *(const float4*)(wr + 8);
        float4 w3 = *(const float4*)(wr + 12);
        float wv[16] = {w0.x,w0.y,w0.z,w0.w, w1.x,w1.y,w1.z,w1.w,
                        w2.x,w2.y,w2.z,w2.w, w3.x,w3.y,w3.z,w3.w};
#pragma unroll
        for (int j = 0; j < 16; ++j)
            Wtl[(cb * 16 + j) * 72 + k] = (short)f2bf(wv[j]);
    }

    {
        const int r  = tid >> 2;
        const int cg = (tid & 3) << 4;
        const int hh = cg >> 5;

        float lsum = 0.f;
        float o[16];
#pragma unroll
        for (int j = 0; j < 16; ++j) o[j] = 0.f;

        for (int p = 0; p < P; ++p) {
            const int pb = bid0 + 8 * p;
            const float* lpp = (const float*)(ws + LPOFF) + (size_t)pb * 128;
            lsum += lpp[hh * 64 + r];
            const _Float16* Opp = (const _Float16*)(ws + OPOFF) + (size_t)pb * 4096;
            union H4 { uint4 u; _Float16 h[8]; };
            H4 x0, x1;
            x0.u = *(const uint4*)(Opp + (size_t)r * 64 + cg);
            x1.u = *(const uint4*)(Opp + (size_t)r * 64 + cg + 8);
#pragma unroll
            for (int j = 0; j < 8; ++j) {
                o[j]     += (float)x0.h[j];
                o[j + 8] += (float)x1.h[j];
            }
        }
        const float inv = 1.0f / lsum;
        short* arow = As + r * 72 + cg;
#pragma unroll
        for (int j = 0; j < 16; ++j) arow[j] = (short)f2bf(o[j] * inv);
    }
    __syncthreads();

    const int lane = tid & 63;
    const int w    = tid >> 6;
    const int l15  = lane & 15;
    const int g    = lane >> 4;
#pragma unroll
    for (int tc = 0; tc < 4; ++tc) {
        const int col = 16 * tc + l15;
        const float bias = bo[col];
        f32x4 accE = {bias, bias, bias, bias};
#pragma unroll
        for (int kk = 0; kk < 2; ++kk) {
            bf16x8 a   = *(const bf16x8*)((char*)As  + (16 * w + l15) * 144 + kk * 64 + 16 * g);
            bf16x8 bfr = *(const bf16x8*)((char*)Wtl + col * 144 + kk * 64 + 16 * g);
            accE = __builtin_amdgcn_mfma_f32_16x16x32_bf16(a, bfr, accE, 0, 0, 0);
        }
        float* ob = out + ((size_t)(b * Nq + q0 + 16 * w + 4 * g)) * 64 + col;
#pragma unroll
        for (int r = 0; r < 4; ++r) ob[(size_t)r * 64] = accE[r];
    }
}

// ---------------------------------------------------------------------------
extern "C" void kernel_launch(void* const* d_in, const int* in_sizes, int n_in,
                              void* d_out, int out_size, void* d_ws, size_t ws_size,
                              hipStream_t stream) {
    const float* x   = (const float*)d_in[0];
    const float* ctx = (const float*)d_in[1];
    const float* Wq  = (const float*)d_in[2];
    const float* Wk  = (const float*)d_in[3];
    const float* Wv  = (const float*)d_in[4];
    const float* Wo  = (const float*)d_in[5];
    const float* bo  = (const float*)d_in[6];
    float* out = (float*)d_out;
    unsigned short* ws = (unsigned short*)d_ws;  // Qs|Kt|Vt|Opart|lpart

    const int P = (ws_size >= WS_NEED3) ? 3 : 2;   // key-split ways (fixed per run)

    dim3 gproj(Bc * Nq / 128, 3);
    proj_kernel<<<gproj, 256, 0, stream>>>(x, ctx, Wq, Wk, Wv, ws);

    flash_kernel<<<dim3(Nq / 64 * Bc * P), 256, 0, stream>>>(ws, P);

    combine_kernel<<<dim3(Nq / 64 * Bc), 256, 0, stream>>>(ws, Wo, bo, out, P);
}